// Round 1
// 103.509 us; speedup vs baseline: 1.0221x; 1.0221x over previous
//
#include <hip/hip_runtime.h>

// Head: single-head causal attention. B=4, T=2048, D=1024, H=64. fp32 in/out.
// R10 (this round): latency/instruction-overhead pass on attn_partial + attn_merge.
//  - attn_partial: static two-tile flow (no dynamic break -> cross-tile
//    scheduling), V fragments prefetched into registers (kst=0 before softmax,
//    kst=1 after P-LDS write) so L2 latency hides under softmax VALU; Opart
//    written via LDS repack as 2 contiguous 1KB dwordx4 stores (was 16 scalar
//    2B stores/lane).
//  - attn_merge: 8 cols/thread (65536 threads, grid 256), Opart read as bf16x8
//    (wave reads contiguous 1KB/instr, was 2B scalar), float4 out stores.
//  - qkv/wt unchanged for attribution.
//
// ws layout (bytes):
//   [0,        393216)   wtf   bf16 [12][128][16][8]   (fragment-ordered W)
//   [393216,  1441792)   qf    bf16 [512][8][16][8]    (fragment-ordered Q)
//   [1441792, 2490368)   kf    bf16 [512][8][16][8]
//   [2490368, 3538944)   vf    bf16 [4][32][4][8][16][8]
//   [3538944, 12451840)  Opart bf16 [4352][16][64]     (gid-indexed)
//   [12451840,12730368)  mpart fp32 [4352][16]
//   [12730368,13008896)  lpart fp32 [4352][16]

typedef __attribute__((ext_vector_type(8))) __bf16 bf16x8;
typedef __attribute__((ext_vector_type(4))) float floatx4;

union BF8 {
    bf16x8 v;
    unsigned short s[8];
    uint4 u;
};
union BF4 {
    unsigned short s[4];
    unsigned long long ull;
};

__device__ inline unsigned short f2bf(float f) {
    unsigned int u = __float_as_uint(f);
    unsigned int r = (u + 0x7fffu + ((u >> 16) & 1u)) >> 16;
    return (unsigned short)r;
}
__device__ inline float bf2f(unsigned short s) {
    unsigned int u = ((unsigned int)s) << 16;
    return __uint_as_float(u);
}

// ---------------------------------------------------------------------------
// Kernel 0: W -> wtf fragment layout (unchanged). Grid 48 = 3 x 16.
// ---------------------------------------------------------------------------
__global__ __launch_bounds__(256) void wt_kernel(const float* __restrict__ Wq,
                                                 const float* __restrict__ Wk,
                                                 const float* __restrict__ Wv,
                                                 unsigned short* __restrict__ wtf) {
    __shared__ __align__(16) unsigned short lt[64 * 72];
    const int tid = threadIdx.x;
    const int sel = blockIdx.x >> 4;
    const int kb = blockIdx.x & 15;
    const float* W = (sel == 0) ? Wq : (sel == 1) ? Wk : Wv;

    const int h = tid & 63;
    const int kr = tid >> 6;
#pragma unroll
    for (int i = 0; i < 16; ++i) {
        const int kkl = kr + i * 4;
        lt[kkl * 72 + h] = f2bf(W[(size_t)(kb * 64 + kkl) * 64 + h]);
    }
    __syncthreads();

#pragma unroll
    for (int s = 0; s < 2; ++s) {
        const int seg = tid + s * 256;
        const int l16 = seg & 15;
        const int rest = seg >> 4;
        const int ko = rest & 7;
        const int hb = rest >> 3;
        const int hh = hb * 16 + l16;
        BF8 o;
#pragma unroll
        for (int j = 0; j < 8; ++j) o.s[j] = lt[(ko * 8 + j) * 72 + hh];
        const int nblk = sel * 4 + hb;
        const int koct = kb * 8 + ko;
        *(uint4*)(wtf + ((size_t)nblk * 128 + koct) * 128 + l16 * 8) = o.u;
    }
}

// ---------------------------------------------------------------------------
// Kernel 1: QKV projection (unchanged). Grid 512 m-tiles(16 rows) x 256 thr.
// ---------------------------------------------------------------------------
__global__ __launch_bounds__(256) void qkv_kernel(const float* __restrict__ x,
                                                  const unsigned short* __restrict__ wtf,
                                                  unsigned short* __restrict__ qf,
                                                  unsigned short* __restrict__ kf,
                                                  unsigned short* __restrict__ vf) {
    __shared__ __align__(16) unsigned short lx[2][16 * 136];
    __shared__ __align__(16) unsigned short lt[16 * 200];
    __shared__ __align__(16) unsigned short vtile[64 * 24];
    const int tid = threadIdx.x;
    const int w = tid >> 6;  // col-group: 48 cols each
    const int lane = tid & 63;
    const int quad = lane >> 4;
    const int l16 = lane & 15;
    const int m0 = blockIdx.x * 16;
    const int b = m0 >> 11;

    const int srow = tid >> 4;  // 0..15
    const int sc = tid & 15;    // float4 slot (2 per thread: sc, sc+16)

    float4 ld[2];
    const float* xbase = x + (size_t)(m0 + srow) * 1024 + sc * 4;

#define LOAD_CHUNK(c)                               \
    {                                               \
        const float* p_ = xbase + (c) * 128;        \
        ld[0] = *(const float4*)(p_);               \
        ld[1] = *(const float4*)(p_ + 64);          \
    }
#define WRITE_CHUNK(buf)                                           \
    {                                                              \
        unsigned short* p_ = &lx[buf][0] + srow * 136 + sc * 4;    \
        BF4 b0_, b1_;                                              \
        b0_.s[0] = f2bf(ld[0].x); b0_.s[1] = f2bf(ld[0].y);        \
        b0_.s[2] = f2bf(ld[0].z); b0_.s[3] = f2bf(ld[0].w);        \
        b1_.s[0] = f2bf(ld[1].x); b1_.s[1] = f2bf(ld[1].y);        \
        b1_.s[2] = f2bf(ld[1].z); b1_.s[3] = f2bf(ld[1].w);        \
        *(unsigned long long*)(p_) = b0_.ull;                      \
        *(unsigned long long*)(p_ + 64) = b1_.ull;                 \
    }

    floatx4 acc[3];
#pragma unroll
    for (int i = 0; i < 3; ++i) acc[i] = (floatx4)(0.0f);

    LOAD_CHUNK(0);
    WRITE_CHUNK(0);
    __syncthreads();

    for (int c = 0; c < 8; ++c) {
        if (c < 7) LOAD_CHUNK(c + 1);
        const unsigned short* lp = &lx[c & 1][0] + l16 * 136 + quad * 8;
#pragma unroll
        for (int kst = 0; kst < 4; ++kst) {
            BF8 a;
            a.u = *(const uint4*)(lp + kst * 32);
            const int koct = c * 16 + kst * 4 + quad;
#pragma unroll
            for (int nt = 0; nt < 3; ++nt) {
                const int nb = w * 3 + nt;
                BF8 bfr;
                bfr.u = *(const uint4*)(wtf + ((size_t)nb * 128 + koct) * 128 + l16 * 8);
                acc[nt] = __builtin_amdgcn_mfma_f32_16x16x32_bf16(a.v, bfr.v, acc[nt], 0, 0, 0);
            }
        }
        if (c < 7) WRITE_CHUNK((c + 1) & 1);
        __syncthreads();
    }

    // epilogue: stash C-tiles. cols 0..127 (q,k) -> lt row-major; 128..191 (v)
    // -> vtile (4 consecutive t packed per lane).
#pragma unroll
    for (int nt = 0; nt < 3; ++nt) {
        const int ngl = w * 48 + nt * 16;
        if (ngl < 128) {
#pragma unroll
            for (int r = 0; r < 4; ++r)
                lt[(quad * 4 + r) * 200 + ngl + l16] = f2bf(acc[nt][r]);
        } else {
            BF4 pk;
#pragma unroll
            for (int r = 0; r < 4; ++r) pk.s[r] = f2bf(acc[nt][r]);
            *(unsigned long long*)&vtile[(ngl - 128 + l16) * 24 + quad * 4] = pk.ull;
        }
    }
    __syncthreads();

    // q/k emission: 256 segs of 16B; 16 consecutive tids -> 256B contiguous.
    {
        const int row = tid & 15;
        const int koct = tid >> 4;  // 0..15
        uint4 seg = *(const uint4*)&lt[row * 200 + koct * 8];
        const size_t tile = blockIdx.x;  // = b*128 + qt
        if (koct < 8)
            *(uint4*)(qf + tile * 1024 + koct * 128 + row * 8) = seg;
        else
            *(uint4*)(kf + tile * 1024 + (koct - 8) * 128 + row * 8) = seg;
    }
    // v emission: 128 segs of 16B (8 consecutive t at fixed h).
    if (tid < 128) {
        const int h = tid >> 1;
        const int sg = tid & 1;
        uint4 seg = *(const uint4*)&vtile[h * 24 + sg * 8];
        const int jt = (m0 & 2047) >> 6;
        const int koct = ((m0 & 63) >> 3) + sg;
        *(uint4*)(vf + (((size_t)(b * 32 + jt) * 4 + (h >> 4)) * 8 + koct) * 128 +
                  (h & 15) * 8) = seg;
    }
#undef LOAD_CHUNK
#undef WRITE_CHUNK
}

// ---------------------------------------------------------------------------
// Kernel 2: flash pass A. R10: static two-tile flow + V register prefetch +
// LDS-packed Opart store. Grid 1088 x 4 waves = 4352 waves, all active.
// ---------------------------------------------------------------------------
__device__ __forceinline__ void attn_tile(int j0, int r0, int b, int lane, int quad,
                                          int l16,
                                          const unsigned short* __restrict__ kf,
                                          const unsigned short* __restrict__ vf,
                                          unsigned short* myp, const BF8* aq,
                                          floatx4* oacc, float* m_i, float* l_i) {
    floatx4 s[4];
#pragma unroll
    for (int nt = 0; nt < 4; ++nt) s[nt] = (floatx4)(0.0f);
#pragma unroll
    for (int kst = 0; kst < 2; ++kst) {
#pragma unroll
        for (int nt = 0; nt < 4; ++nt) {
            BF8 bk;
            bk.u = *(const uint4*)(kf + (size_t)(b * 128 + (j0 >> 4) + nt) * 1024 +
                                   kst * 512 + lane * 8);
            s[nt] = __builtin_amdgcn_mfma_f32_16x16x32_bf16(aq[kst].v, bk.v, s[nt], 0, 0, 0);
        }
    }

    // V prefetch (kst=0): independent of softmax -> issues now, lands under
    // the ~300 VALU cycles of softmax below.
    BF8 bv0[4];
#pragma unroll
    for (int nt = 0; nt < 4; ++nt)
        bv0[nt].u = *(const uint4*)(vf + ((size_t)(b * 32 + (j0 >> 6)) * 4 + nt) * 1024 +
                                    lane * 8);

    float sv[4][4];
    const bool masked = (j0 + 63 > r0);
#pragma unroll
    for (int nt = 0; nt < 4; ++nt)
#pragma unroll
        for (int r = 0; r < 4; ++r) {
            float val = s[nt][r] * 0.125f;
            if (masked) {
                int key = j0 + nt * 16 + l16;
                int qr = r0 + quad * 4 + r;
                if (key > qr) val = -3.0e38f;
            }
            sv[nt][r] = val;
        }

    float alpha[4];
#pragma unroll
    for (int r = 0; r < 4; ++r) {
        float mx = fmaxf(fmaxf(sv[0][r], sv[1][r]), fmaxf(sv[2][r], sv[3][r]));
        mx = fmaxf(mx, __shfl_xor(mx, 1));
        mx = fmaxf(mx, __shfl_xor(mx, 2));
        mx = fmaxf(mx, __shfl_xor(mx, 4));
        mx = fmaxf(mx, __shfl_xor(mx, 8));
        float mn = fmaxf(m_i[r], mx);
        alpha[r] = __expf(m_i[r] - mn);
        m_i[r] = mn;
    }
    float rs[4] = {0.f, 0.f, 0.f, 0.f};
#pragma unroll
    for (int nt = 0; nt < 4; ++nt)
#pragma unroll
        for (int r = 0; r < 4; ++r) {
            float p = __expf(sv[nt][r] - m_i[r]);
            sv[nt][r] = p;
            rs[r] += p;
        }
#pragma unroll
    for (int r = 0; r < 4; ++r) {
        float t2 = rs[r];
        t2 += __shfl_xor(t2, 1);
        t2 += __shfl_xor(t2, 2);
        t2 += __shfl_xor(t2, 4);
        t2 += __shfl_xor(t2, 8);
        l_i[r] = l_i[r] * alpha[r] + t2;
    }
#pragma unroll
    for (int nt = 0; nt < 4; ++nt)
#pragma unroll
        for (int r = 0; r < 4; ++r) oacc[nt][r] *= alpha[r];

#pragma unroll
    for (int nt = 0; nt < 4; ++nt)
#pragma unroll
        for (int r = 0; r < 4; ++r)
            myp[(quad * 4 + r) * 72 + nt * 16 + l16] = f2bf(sv[nt][r]);

    // V prefetch (kst=1): lands under the kst=0 ds_read + 4 MFMAs.
    BF8 bv1[4];
#pragma unroll
    for (int nt = 0; nt < 4; ++nt)
        bv1[nt].u = *(const uint4*)(vf + ((size_t)(b * 32 + (j0 >> 6)) * 4 + nt) * 1024 +
                                    512 + lane * 8);

    {
        BF8 ap;
        ap.u = *(const uint4*)(myp + l16 * 72 + quad * 8);
#pragma unroll
        for (int nt = 0; nt < 4; ++nt)
            oacc[nt] = __builtin_amdgcn_mfma_f32_16x16x32_bf16(ap.v, bv0[nt].v, oacc[nt], 0, 0, 0);
    }
    {
        BF8 ap;
        ap.u = *(const uint4*)(myp + l16 * 72 + 32 + quad * 8);
#pragma unroll
        for (int nt = 0; nt < 4; ++nt)
            oacc[nt] = __builtin_amdgcn_mfma_f32_16x16x32_bf16(ap.v, bv1[nt].v, oacc[nt], 0, 0, 0);
    }
}

__global__ __launch_bounds__(256) void attn_partial(const unsigned short* __restrict__ qf,
                                                    const unsigned short* __restrict__ kf,
                                                    const unsigned short* __restrict__ vf,
                                                    unsigned short* __restrict__ Opart,
                                                    float* __restrict__ mpart,
                                                    float* __restrict__ lpart) {
    __shared__ __align__(16) unsigned short lds_p[4 * 16 * 72];
    const int tid = threadIdx.x;
    const int w = tid >> 6;
    const int lane = tid & 63;
    const int quad = lane >> 4;
    const int l16 = lane & 15;
    const int gid = blockIdx.x * 4 + w;  // 0..4351
    const int b = gid / 1088;
    const int rem = gid - b * 1088;
    int g = (int)((sqrtf((float)(4 * rem + 1)) - 1.0f) * 0.5f);
    while (4 * (g + 1) * (g + 2) <= rem) ++g;
    while (4 * g * (g + 1) > rem) --g;
    const int off = rem - 4 * g * (g + 1);
    const int nc = g + 1;
    const int qti = off / nc;
    const int kc = off - qti * nc;
    const int qt = g * 8 + qti;
    const int r0 = qt * 16;

    BF8 aq[2];
    {
        const unsigned short* qtile = qf + (size_t)(b * 128 + qt) * 1024;
        aq[0].u = *(const uint4*)(qtile + lane * 8);
        aq[1].u = *(const uint4*)(qtile + 512 + lane * 8);
    }

    floatx4 oacc[4];
#pragma unroll
    for (int nt = 0; nt < 4; ++nt) oacc[nt] = (floatx4)(0.0f);
    float m_i[4], l_i[4];
#pragma unroll
    for (int r = 0; r < 4; ++r) { m_i[r] = -3.0e38f; l_i[r] = 0.0f; }

    unsigned short* myp = lds_p + w * (16 * 72);

    // Tile 0 always valid (kc*128 <= r0 by construction); tile 1 iff any of
    // its keys are unmasked for this q-tile.
    const int j0a = kc * 128;
    const bool has2 = (j0a + 64 <= r0 + 15);
    attn_tile(j0a, r0, b, lane, quad, l16, kf, vf, myp, aq, oacc, m_i, l_i);
    if (has2)
        attn_tile(j0a + 64, r0, b, lane, quad, l16, kf, vf, myp, aq, oacc, m_i, l_i);

    // Pack oacc -> LDS (bf16, rows stride 72) -> two contiguous 1KB stores.
#pragma unroll
    for (int nt = 0; nt < 4; ++nt)
#pragma unroll
        for (int r = 0; r < 4; ++r)
            myp[(quad * 4 + r) * 72 + nt * 16 + l16] = f2bf(oacc[nt][r]);
    const size_t ob = (size_t)gid * 1024;
    {
        const int row0 = lane >> 3;
        const int c0 = (lane & 7) * 8;
        uint4 a0 = *(const uint4*)(myp + row0 * 72 + c0);
        uint4 a1 = *(const uint4*)(myp + (row0 + 8) * 72 + c0);
        *(uint4*)(Opart + ob + lane * 8) = a0;
        *(uint4*)(Opart + ob + 512 + lane * 8) = a1;
    }
    if (l16 == 0) {
#pragma unroll
        for (int r = 0; r < 4; ++r) {
            mpart[gid * 16 + quad * 4 + r] = m_i[r];
            lpart[gid * 16 + quad * 4 + r] = l_i[r];
        }
    }
}

// ---------------------------------------------------------------------------
// Kernel 3: merge. R10: 8 cols/thread, bf16x8 Opart loads (contiguous 1KB per
// wave-instruction), float4 out stores. 65536 threads = 256 blocks.
// ---------------------------------------------------------------------------
__global__ __launch_bounds__(256) void attn_merge(const unsigned short* __restrict__ Opart,
                                                  const float* __restrict__ mpart,
                                                  const float* __restrict__ lpart,
                                                  float* __restrict__ out) {
    const int e = blockIdx.x * 256 + threadIdx.x;  // 0..65535
    const int cg = e & 7;            // col group of 8
    const int row16 = (e >> 3) & 15;
    const int qt = (e >> 7) & 127;
    const int b = e >> 14;
    const int g = qt >> 3;
    const int nc = g + 1;
    const int base_id = b * 1088 + 4 * g * (g + 1) + (qt & 7) * nc;

    float M = -3.0e38f, L = 0.0f;
    float O[8];
#pragma unroll
    for (int j = 0; j < 8; ++j) O[j] = 0.0f;

#pragma unroll 4
    for (int c = 0; c < nc; ++c) {
        const int id = base_id + c;
        const float m_c = mpart[id * 16 + row16];
        const float l_c = lpart[id * 16 + row16];
        BF8 ov;
        ov.u = *(const uint4*)(Opart + (size_t)id * 1024 + row16 * 64 + cg * 8);
        const float Mn = fmaxf(M, m_c);
        const float a = __expf(M - Mn);
        const float ec = __expf(m_c - Mn);
        L = L * a + ec * l_c;
#pragma unroll
        for (int j = 0; j < 8; ++j) O[j] = O[j] * a + ec * bf2f(ov.s[j]);
        M = Mn;
    }
    const float inv = 1.0f / L;
    float4 lo, hi;
    lo.x = O[0] * inv; lo.y = O[1] * inv; lo.z = O[2] * inv; lo.w = O[3] * inv;
    hi.x = O[4] * inv; hi.y = O[5] * inv; hi.z = O[6] * inv; hi.w = O[7] * inv;
    float* op = out + ((size_t)((b * 128 + qt) * 16 + row16)) * 64 + cg * 8;
    *(float4*)op = lo;
    *(float4*)(op + 4) = hi;
}

extern "C" void kernel_launch(void* const* d_in, const int* in_sizes, int n_in,
                              void* d_out, int out_size, void* d_ws, size_t ws_size,
                              hipStream_t stream) {
    const float* x = (const float*)d_in[0];
    const float* Wq = (const float*)d_in[1];
    const float* Wk = (const float*)d_in[2];
    const float* Wv = (const float*)d_in[3];
    float* out = (float*)d_out;

    char* ws = (char*)d_ws;
    unsigned short* wtf = (unsigned short*)(ws);
    unsigned short* qf = (unsigned short*)(ws + 393216);
    unsigned short* kf = (unsigned short*)(ws + 1441792);
    unsigned short* vf = (unsigned short*)(ws + 2490368);
    unsigned short* Opart = (unsigned short*)(ws + 3538944);
    float* mpart = (float*)(ws + 12451840ull);
    float* lpart = (float*)(ws + 12730368ull);

    hipLaunchKernelGGL(wt_kernel, dim3(48), dim3(256), 0, stream, Wq, Wk, Wv, wtf);
    hipLaunchKernelGGL(qkv_kernel, dim3(512), dim3(256), 0, stream, x, wtf, qf, kf, vf);
    hipLaunchKernelGGL(attn_partial, dim3(1088), dim3(256), 0, stream, qf, kf, vf, Opart, mpart, lpart);
    hipLaunchKernelGGL(attn_merge, dim3(256), dim3(256), 0, stream, Opart, mpart, lpart, out);
}